// Round 1
// baseline (343.938 us; speedup 1.0000x reference)
//
#include <hip/hip_runtime.h>
#include <hip/hip_bf16.h>

#define BHN 64
#define TT 1024
#define DD 64
#define MAXREL 16
#define NV 33
#define QBLK 16
#define PSTRIDE 1028
#define SCALE 0.125f

typedef short bf16x8 __attribute__((ext_vector_type(8)));
typedef float f32x4 __attribute__((ext_vector_type(4)));

static __device__ inline short f2bf(float f) {
    union { float f; unsigned u; } x; x.f = f;
    unsigned u = x.u;
    u += 0x7fff + ((u >> 16) & 1);   // round-to-nearest-even
    return (short)(u >> 16);
}
static __device__ inline float bf2f(short s) {
    union { unsigned u; float f; } x;
    x.u = ((unsigned)(unsigned short)s) << 16;
    return x.f;
}
static __device__ inline bf16x8 pack8(float4 a, float4 b) {
    bf16x8 r;
    r[0] = f2bf(a.x); r[1] = f2bf(a.y); r[2] = f2bf(a.z); r[3] = f2bf(a.w);
    r[4] = f2bf(b.x); r[5] = f2bf(b.y); r[6] = f2bf(b.z); r[7] = f2bf(b.w);
    return r;
}

__global__ __launch_bounds__(256, 2)
void relattn_kernel(const float* __restrict__ q_g,
                    const float* __restrict__ k_g,
                    const float* __restrict__ v_g,
                    const float* __restrict__ ek_g,
                    const float* __restrict__ ev_g,
                    float* __restrict__ out_g,
                    float* __restrict__ attn_g) {
    __shared__ float p_lds[QBLK][PSTRIDE];   // 65792 B
    __shared__ short Qb[QBLK][DD];           // 2048 B (bf16 bits)
    __shared__ float embsh[NV * DD];         // 8448 B (emb_k then emb_v)
    __shared__ float qe_lds[QBLK * NV];      // 2112 B
    __shared__ float w_lds[QBLK * NV];       // 2112 B
    __shared__ float inv_lds[QBLK];          // 64 B

    const int t    = threadIdx.x;
    const int bh   = blockIdx.x >> 6;
    const int qt   = blockIdx.x & 63;
    const int q0   = qt * QBLK;
    const int wave = t >> 6;
    const int lane = t & 63;

    // ---- Phase A: stage Q (bf16) and emb_k (f32) ----
    {
        const float* qp = q_g + ((size_t)bh * TT + q0) * DD + t * 4;
        float4 qv = *(const float4*)qp;
        short* dst = &Qb[0][0] + t * 4;
        dst[0] = f2bf(qv.x); dst[1] = f2bf(qv.y);
        dst[2] = f2bf(qv.z); dst[3] = f2bf(qv.w);
        for (int i = t; i < (NV * DD) / 4; i += 256) {
            float4 e = *(const float4*)(ek_g + (size_t)i * 4);
            *(float4*)(embsh + i * 4) = e;
        }
    }
    __syncthreads();

    // ---- Phase B: qe[r][v] = (q[r] . emb_k[v]) / 8 ----
    for (int i = t; i < QBLK * NV; i += 256) {
        int r = i / NV, v = i - r * NV;
        float acc = 0.f;
        #pragma unroll 8
        for (int d = 0; d < DD; ++d)
            acc += bf2f(Qb[r][d]) * embsh[v * DD + d];
        qe_lds[i] = acc * SCALE;
    }
    __syncthreads();

    // ---- Phase C: logits = (Q K^T)/8 + qe, into p_lds ----
    {
        const int ar  = lane & 15;
        const int akg = lane >> 4;
        bf16x8 aF0 = *(const bf16x8*)&Qb[ar][akg * 8];
        bf16x8 aF1 = *(const bf16x8*)&Qb[ar][32 + akg * 8];
        for (int nt = 0; nt < 16; ++nt) {
            int s0 = wave * 256 + nt * 16;
            const float* kp = k_g + ((size_t)bh * TT + s0 + ar) * DD + akg * 8;
            float4 kv0 = *(const float4*)(kp);
            float4 kv1 = *(const float4*)(kp + 4);
            float4 kv2 = *(const float4*)(kp + 32);
            float4 kv3 = *(const float4*)(kp + 36);
            bf16x8 bF0 = pack8(kv0, kv1);
            bf16x8 bF1 = pack8(kv2, kv3);
            f32x4 acc = {0.f, 0.f, 0.f, 0.f};
            acc = __builtin_amdgcn_mfma_f32_16x16x32_bf16(aF0, bF0, acc, 0, 0, 0);
            acc = __builtin_amdgcn_mfma_f32_16x16x32_bf16(aF1, bF1, acc, 0, 0, 0);
            int sC = s0 + ar;
            int rb = akg * 4;
            #pragma unroll
            for (int j = 0; j < 4; ++j) {
                int r  = rb + j;
                int tq = q0 + r;
                int dlt = sC - tq;
                dlt = dlt < -MAXREL ? -MAXREL : (dlt > MAXREL ? MAXREL : dlt);
                p_lds[r][sC] = acc[j] * SCALE + qe_lds[r * NV + dlt + MAXREL];
            }
        }
    }
    __syncthreads();

    // ---- Phase D: row softmax + w (prefix/suffix/middles) ----
    {
        const int r  = t >> 4;
        const int l  = t & 15;
        const int tq = q0 + r;
        float m = -1e30f;
        for (int i = 0; i < 64; ++i) m = fmaxf(m, p_lds[r][l + 16 * i]);
        #pragma unroll
        for (int off = 1; off < 16; off <<= 1) m = fmaxf(m, __shfl_xor(m, off));
        float sum = 0.f, pref = 0.f, suff = 0.f;
        for (int i = 0; i < 64; ++i) {
            int s = l + 16 * i;
            float p = __expf(p_lds[r][s] - m);
            p_lds[r][s] = p;
            sum += p;
            if (s <= tq - MAXREL) pref += p;
            if (s >= tq + MAXREL) suff += p;
        }
        #pragma unroll
        for (int off = 1; off < 16; off <<= 1) {
            sum  += __shfl_xor(sum, off);
            pref += __shfl_xor(pref, off);
            suff += __shfl_xor(suff, off);
        }
        float inv = 1.0f / sum;
        if (l == 0) {
            inv_lds[r] = inv;
            w_lds[r * NV + 0]      = pref * inv;
            w_lds[r * NV + NV - 1] = suff * inv;
        }
        for (int mm = 1 + l; mm < NV - 1; mm += 16) {
            int s = tq + mm - MAXREL;
            float wv = (s >= 0 && s < TT) ? p_lds[r][s] * inv : 0.f;
            w_lds[r * NV + mm] = wv;
        }
    }
    __syncthreads();

    // ---- Phase E: write normalized attn (coalesced) + stage emb_v ----
    {
        for (int i = t; i < (NV * DD) / 4; i += 256) {
            float4 e = *(const float4*)(ev_g + (size_t)i * 4);
            *(float4*)(embsh + i * 4) = e;
        }
        float* ab = attn_g + ((size_t)bh * TT + q0) * TT;
        const int col = t * 4;
        #pragma unroll 4
        for (int i = 0; i < QBLK; ++i) {
            float inv = inv_lds[i];
            float4 p = *(const float4*)&p_lds[i][col];
            float4 o;
            o.x = p.x * inv; o.y = p.y * inv; o.z = p.z * inv; o.w = p.w * inv;
            *(float4*)(ab + (size_t)i * TT + col) = o;
        }
    }
    __syncthreads();

    // ---- Phase F: out = (P V)*inv + w . emb_v ----
    {
        const int lc   = lane & 15;
        const int akg  = lane >> 4;
        const int dcol = wave * 16 + lc;
        f32x4 acc = {0.f, 0.f, 0.f, 0.f};
        for (int kt = 0; kt < 32; ++kt) {
            int sbase = kt * 32 + akg * 8;
            const float* pp = &p_lds[lc][sbase];
            float4 a0 = *(const float4*)pp;
            float4 a1 = *(const float4*)(pp + 4);
            bf16x8 aF = pack8(a0, a1);
            const float* vp = v_g + ((size_t)bh * TT + sbase) * DD + dcol;
            float vv[8];
            #pragma unroll
            for (int j = 0; j < 8; ++j) vv[j] = vp[(size_t)j * DD];
            bf16x8 bF;
            #pragma unroll
            for (int j = 0; j < 8; ++j) bF[j] = f2bf(vv[j]);
            acc = __builtin_amdgcn_mfma_f32_16x16x32_bf16(aF, bF, acc, 0, 0, 0);
        }
        const int rb = akg * 4;
        #pragma unroll
        for (int j = 0; j < 4; ++j) {
            int r = rb + j;
            float o = acc[j] * inv_lds[r];
            for (int v = 0; v < NV; ++v)
                o += w_lds[r * NV + v] * embsh[v * DD + dcol];
            out_g[((size_t)bh * TT + q0 + r) * DD + dcol] = o;
        }
    }
}

extern "C" void kernel_launch(void* const* d_in, const int* in_sizes, int n_in,
                              void* d_out, int out_size, void* d_ws, size_t ws_size,
                              hipStream_t stream) {
    const float* q  = (const float*)d_in[0];
    const float* k  = (const float*)d_in[1];
    const float* v  = (const float*)d_in[2];
    const float* ek = (const float*)d_in[3];
    const float* ev = (const float*)d_in[4];
    float* out  = (float*)d_out;
    float* attn = out + (size_t)4 * 16 * 1024 * 64;
    relattn_kernel<<<dim3(4096), dim3(256), 0, stream>>>(q, k, v, ek, ev, out, attn);
}

// Round 2
// 278.049 us; speedup vs baseline: 1.2370x; 1.2370x over previous
//
#include <hip/hip_runtime.h>

#define TT 1024
#define DD 64
#define MAXREL 16
#define NV 33
#define QBLK 16
#define PSTRIDE 1028
#define SCALE 0.125f
#define BH 64

typedef short bf16x8 __attribute__((ext_vector_type(8)));
typedef short bf16x4 __attribute__((ext_vector_type(4)));
typedef float f32x4 __attribute__((ext_vector_type(4)));

static __device__ inline short f2bf(float f) {
    union { float f; unsigned u; } x; x.f = f;
    unsigned u = x.u;
    u += 0x7fff + ((u >> 16) & 1);   // RNE
    return (short)(u >> 16);
}
static __device__ inline float bf2f(short s) {
    union { unsigned u; float f; } x;
    x.u = ((unsigned)(unsigned short)s) << 16;
    return x.f;
}

// ---- pre-kernel 1: K f32 -> bf16 (same layout) ----
__global__ __launch_bounds__(256)
void convk_kernel(const float* __restrict__ src, short* __restrict__ dst) {
    size_t i = (size_t)blockIdx.x * 256 + threadIdx.x;   // groups of 8 elements
    const float4* s = (const float4*)(src + i * 8);
    float4 a = s[0], b = s[1];
    bf16x8 r;
    r[0]=f2bf(a.x); r[1]=f2bf(a.y); r[2]=f2bf(a.z); r[3]=f2bf(a.w);
    r[4]=f2bf(b.x); r[5]=f2bf(b.y); r[6]=f2bf(b.z); r[7]=f2bf(b.w);
    *(bf16x8*)(dst + i * 8) = r;
}

// ---- pre-kernel 2: V [bh][s][d] f32 -> vt [bh][d][s] bf16 ----
__global__ __launch_bounds__(256)
void transv_kernel(const float* __restrict__ v, short* __restrict__ vt) {
    int bh = blockIdx.x >> 4;
    int st = blockIdx.x & 15;
    int wave = threadIdx.x >> 6, lane = threadIdx.x & 63;
    int s0 = st * 64 + wave * 16;
    const float* vp = v + ((size_t)bh * TT + s0) * DD + lane;  // lane = d
    bf16x8 lo, hi;
    #pragma unroll
    for (int e = 0; e < 8; ++e) lo[e] = f2bf(vp[(size_t)e * DD]);
    #pragma unroll
    for (int e = 0; e < 8; ++e) hi[e] = f2bf(vp[(size_t)(e + 8) * DD]);
    short* dp = vt + ((size_t)bh * DD + lane) * TT + s0;
    *(bf16x8*)dp = lo;
    *(bf16x8*)(dp + 8) = hi;
}

__global__ __launch_bounds__(256, 2)
void relattn_kernel(const float* __restrict__ q_g,
                    const short* __restrict__ kb,
                    const short* __restrict__ vt,
                    const float* __restrict__ ek_g,
                    const float* __restrict__ ev_g,
                    float* __restrict__ out_g,
                    float* __restrict__ attn_g) {
    __shared__ __align__(16) char pbuf[QBLK * PSTRIDE * 4];  // f32 logits, then bf16 P (aliased)
    __shared__ short Qb[QBLK][DD];
    __shared__ float embsh[NV * DD];
    __shared__ float qe_lds[QBLK * NV];
    __shared__ float w_lds[QBLK * NV];    // UNnormalized w
    __shared__ float inv_lds[QBLK];

    float* p_f32 = (float*)pbuf;

    const int t    = threadIdx.x;
    const int bid  = blockIdx.x;
    const int wg   = ((bid & 7) << 9) | (bid >> 3);   // XCD swizzle (4096 % 8 == 0)
    const int bh   = wg >> 6;
    const int q0   = (wg & 63) * QBLK;
    const int wave = t >> 6;
    const int lane = t & 63;

    // ---- Phase A: stage Q (bf16) + emb_k ----
    {
        const float* qp = q_g + ((size_t)bh * TT + q0) * DD + t * 4;
        float4 qv = *(const float4*)qp;
        bf16x4 q4;
        q4[0]=f2bf(qv.x); q4[1]=f2bf(qv.y); q4[2]=f2bf(qv.z); q4[3]=f2bf(qv.w);
        *(bf16x4*)(&Qb[0][0] + t * 4) = q4;
        for (int i = t; i < (NV * DD) / 4; i += 256)
            ((float4*)embsh)[i] = ((const float4*)ek_g)[i];
    }
    __syncthreads();

    // ---- Phase B: qe[r][v] = (q[r].emb_k[v])/8 ----
    for (int i = t; i < QBLK * NV; i += 256) {
        int r = i / NV, v = i - r * NV;
        float acc = 0.f;
        #pragma unroll 8
        for (int d = 0; d < DD; ++d)
            acc += bf2f(Qb[r][d]) * embsh[v * DD + d];
        qe_lds[i] = acc * SCALE;
    }
    __syncthreads();

    // ---- Phase C: logits into p_f32 (K frags direct from global bf16) ----
    {
        const int ar = lane & 15, akg = lane >> 4;
        bf16x8 aF0 = *(const bf16x8*)&Qb[ar][akg * 8];
        bf16x8 aF1 = *(const bf16x8*)&Qb[ar][32 + akg * 8];
        const short* kbase = kb + (size_t)bh * TT * DD;
        #pragma unroll 2
        for (int nt = 0; nt < 16; ++nt) {
            int s0 = wave * 256 + nt * 16;
            const short* kp = kbase + (s0 + ar) * DD + akg * 8;
            bf16x8 bF0 = *(const bf16x8*)kp;
            bf16x8 bF1 = *(const bf16x8*)(kp + 32);
            f32x4 acc = {0.f, 0.f, 0.f, 0.f};
            acc = __builtin_amdgcn_mfma_f32_16x16x32_bf16(aF0, bF0, acc, 0, 0, 0);
            acc = __builtin_amdgcn_mfma_f32_16x16x32_bf16(aF1, bF1, acc, 0, 0, 0);
            int sC = s0 + ar;
            int rb = akg * 4;
            #pragma unroll
            for (int j = 0; j < 4; ++j) {
                int r = rb + j;
                int dlt = sC - (q0 + r);
                dlt = dlt < -MAXREL ? -MAXREL : (dlt > MAXREL ? MAXREL : dlt);
                p_f32[r * PSTRIDE + sC] = acc[j] * SCALE + qe_lds[r * NV + dlt + MAXREL];
            }
        }
    }
    __syncthreads();

    // ---- Phase D part 1: exp (m=0; logits bounded), sums, w, attn write ----
    float4 pv[4][4];
    {
        float* ab = attn_g + ((size_t)bh * TT + q0) * TT;
        #pragma unroll
        for (int j = 0; j < 4; ++j) {
            const int r  = wave * 4 + j;
            const int tq = q0 + r;
            if (lane < 31) w_lds[r * NV + 1 + lane] = 0.f;
            float sum = 0.f, pref = 0.f, suff = 0.f;
            #pragma unroll
            for (int i = 0; i < 4; ++i) {
                float4 x = *(const float4*)&p_f32[r * PSTRIDE + lane * 4 + 256 * i];
                float4 e;
                e.x = __expf(x.x); e.y = __expf(x.y);
                e.z = __expf(x.z); e.w = __expf(x.w);
                pv[j][i] = e;
                sum += (e.x + e.y) + (e.z + e.w);
                int sb = lane * 4 + 256 * i;
                if (sb + 0 <= tq - MAXREL) pref += e.x;
                if (sb + 1 <= tq - MAXREL) pref += e.y;
                if (sb + 2 <= tq - MAXREL) pref += e.z;
                if (sb + 3 <= tq - MAXREL) pref += e.w;
                if (sb + 0 >= tq + MAXREL) suff += e.x;
                if (sb + 1 >= tq + MAXREL) suff += e.y;
                if (sb + 2 >= tq + MAXREL) suff += e.z;
                if (sb + 3 >= tq + MAXREL) suff += e.w;
                if (256 * i + 255 >= tq - 15 && 256 * i <= tq + 15) {
                    int d0 = sb + 0 - tq;
                    if (d0 > -MAXREL && d0 < MAXREL) w_lds[r * NV + d0 + MAXREL] = e.x;
                    int d1 = sb + 1 - tq;
                    if (d1 > -MAXREL && d1 < MAXREL) w_lds[r * NV + d1 + MAXREL] = e.y;
                    int d2 = sb + 2 - tq;
                    if (d2 > -MAXREL && d2 < MAXREL) w_lds[r * NV + d2 + MAXREL] = e.z;
                    int d3 = sb + 3 - tq;
                    if (d3 > -MAXREL && d3 < MAXREL) w_lds[r * NV + d3 + MAXREL] = e.w;
                }
            }
            #pragma unroll
            for (int off = 32; off; off >>= 1) {
                sum  += __shfl_xor(sum, off);
                pref += __shfl_xor(pref, off);
                suff += __shfl_xor(suff, off);
            }
            float inv = 1.0f / sum;
            if (lane == 0) {
                inv_lds[r] = inv;
                w_lds[r * NV]      = pref;
                w_lds[r * NV + 32] = suff;
            }
            #pragma unroll
            for (int i = 0; i < 4; ++i) {
                float4 e = pv[j][i];
                float4 o;
                o.x = e.x * inv; o.y = e.y * inv; o.z = e.z * inv; o.w = e.w * inv;
                *(float4*)(ab + (size_t)r * TT + lane * 4 + 256 * i) = o;
            }
        }
    }
    __syncthreads();

    // ---- Phase D part 2: stage emb_v; write bf16 P (swizzled) over pbuf ----
    for (int i = t; i < (NV * DD) / 4; i += 256)
        ((float4*)embsh)[i] = ((const float4*)ev_g)[i];
    #pragma unroll
    for (int j = 0; j < 4; ++j) {
        const int r = wave * 4 + j;
        char* rowb = pbuf + r * 2048;
        #pragma unroll
        for (int i = 0; i < 4; ++i) {
            float4 e = pv[j][i];
            bf16x4 b;
            b[0]=f2bf(e.x); b[1]=f2bf(e.y); b[2]=f2bf(e.z); b[3]=f2bf(e.w);
            int off = (512 * i + 8 * lane) ^ ((r & 7) << 4);
            *(bf16x4*)(rowb + off) = b;
        }
    }
    __syncthreads();

    // ---- Phase F: out = inv * (P V + w . emb_v) ----
    {
        const int lc = lane & 15, a = lane >> 4;
        const int dcol = wave * 16 + lc;
        const short* vbase = vt + ((size_t)bh * DD + dcol) * TT;
        f32x4 acc = {0.f, 0.f, 0.f, 0.f};
        #pragma unroll 4
        for (int kt = 0; kt < 32; ++kt) {
            int off = (kt * 64 + a * 16) ^ ((lc & 7) << 4);
            bf16x8 aF = *(const bf16x8*)(pbuf + lc * 2048 + off);
            bf16x8 bF = *(const bf16x8*)(vbase + kt * 32 + a * 8);
            acc = __builtin_amdgcn_mfma_f32_16x16x32_bf16(aF, bF, acc, 0, 0, 0);
        }
        const int rb = a * 4;
        #pragma unroll
        for (int j = 0; j < 4; ++j) {
            const int r = rb + j;
            float o = acc[j];
            #pragma unroll 8
            for (int v = 0; v < NV; ++v)
                o += w_lds[r * NV + v] * embsh[v * DD + dcol];
            out_g[((size_t)bh * TT + q0 + r) * DD + dcol] = o * inv_lds[r];
        }
    }
}

extern "C" void kernel_launch(void* const* d_in, const int* in_sizes, int n_in,
                              void* d_out, int out_size, void* d_ws, size_t ws_size,
                              hipStream_t stream) {
    const float* q  = (const float*)d_in[0];
    const float* k  = (const float*)d_in[1];
    const float* v  = (const float*)d_in[2];
    const float* ek = (const float*)d_in[3];
    const float* ev = (const float*)d_in[4];
    float* out  = (float*)d_out;
    float* attn = out + (size_t)BH * TT * DD;

    short* kbuf = (short*)d_ws;                          //  8.4 MB
    short* vtb  = kbuf + (size_t)BH * TT * DD;           //  8.4 MB

    convk_kernel<<<dim3(2048), dim3(256), 0, stream>>>(k, kbuf);
    transv_kernel<<<dim3(1024), dim3(256), 0, stream>>>(v, vtb);
    relattn_kernel<<<dim3(4096), dim3(256), 0, stream>>>(q, kbuf, vtb, ek, ev, out, attn);
}

// Round 3
// 222.756 us; speedup vs baseline: 1.5440x; 1.2482x over previous
//
#include <hip/hip_runtime.h>

#define TT 1024
#define DD 64
#define MAXREL 16
#define NV 33
#define QBLK 16
#define SCALE 0.125f
#define BH 64
#define ESTR 68   // padded emb stride (floats)
#define QSTR 72   // padded Qb stride (shorts)

typedef short bf16x8 __attribute__((ext_vector_type(8)));
typedef short bf16x4 __attribute__((ext_vector_type(4)));
typedef float f32x4 __attribute__((ext_vector_type(4)));

static __device__ inline short f2bf(float f) {
    union { float f; unsigned u; } x; x.f = f;
    unsigned u = x.u;
    u += 0x7fff + ((u >> 16) & 1);   // RNE
    return (short)(u >> 16);
}
static __device__ inline float bf2f(short s) {
    union { unsigned u; float f; } x;
    x.u = ((unsigned)(unsigned short)s) << 16;
    return x.f;
}

// ---- pre-kernel 1: K f32 -> bf16 ----
__global__ __launch_bounds__(256)
void convk_kernel(const float* __restrict__ src, short* __restrict__ dst) {
    size_t i = (size_t)blockIdx.x * 256 + threadIdx.x;
    const float4* s = (const float4*)(src + i * 8);
    float4 a = s[0], b = s[1];
    bf16x8 r;
    r[0]=f2bf(a.x); r[1]=f2bf(a.y); r[2]=f2bf(a.z); r[3]=f2bf(a.w);
    r[4]=f2bf(b.x); r[5]=f2bf(b.y); r[6]=f2bf(b.z); r[7]=f2bf(b.w);
    *(bf16x8*)(dst + i * 8) = r;
}

// ---- pre-kernel 2: V [bh][s][d] f32 -> vt [bh][d][s] bf16 ----
__global__ __launch_bounds__(256)
void transv_kernel(const float* __restrict__ v, short* __restrict__ vt) {
    int bh = blockIdx.x >> 4;
    int st = blockIdx.x & 15;
    int wave = threadIdx.x >> 6, lane = threadIdx.x & 63;
    int s0 = st * 64 + wave * 16;
    const float* vp = v + ((size_t)bh * TT + s0) * DD + lane;
    bf16x8 lo, hi;
    #pragma unroll
    for (int e = 0; e < 8; ++e) lo[e] = f2bf(vp[(size_t)e * DD]);
    #pragma unroll
    for (int e = 0; e < 8; ++e) hi[e] = f2bf(vp[(size_t)(e + 8) * DD]);
    short* dp = vt + ((size_t)bh * DD + lane) * TT + s0;
    *(bf16x8*)dp = lo;
    *(bf16x8*)(dp + 8) = hi;
}

__global__ __launch_bounds__(256, 3)
void relattn_kernel(const float* __restrict__ q_g,
                    const short* __restrict__ kb,
                    const short* __restrict__ vt,
                    const float* __restrict__ ek_g,
                    const float* __restrict__ ev_g,
                    float* __restrict__ out_g,
                    float* __restrict__ attn_g) {
    __shared__ __align__(16) char pbuf[QBLK * 2048];       // bf16 P, swizzled rows
    __shared__ short Qb[QBLK][QSTR];                       // 2304 B
    __shared__ float embsh[NV * ESTR];                     // 8976 B
    __shared__ float qe_lds[QBLK * NV];                    // 2112 B
    __shared__ float w_lds[QBLK * NV];                     // 2112 B (unnormalized)
    __shared__ float inv_lds[QBLK];

    const int t    = threadIdx.x;
    const int bid  = blockIdx.x;
    const int wg   = ((bid & 7) << 9) | (bid >> 3);        // XCD swizzle
    const int bh   = wg >> 6;
    const int q0   = (wg & 63) * QBLK;
    const int wave = t >> 6;
    const int lane = t & 63;

    // ---- Phase A: stage Q (bf16), emb_k (padded), zero w ----
    {
        const float* qp = q_g + ((size_t)bh * TT + q0) * DD + t * 4;
        float4 qv = *(const float4*)qp;
        bf16x4 q4;
        q4[0]=f2bf(qv.x); q4[1]=f2bf(qv.y); q4[2]=f2bf(qv.z); q4[3]=f2bf(qv.w);
        *(bf16x4*)(&Qb[t >> 4][(t & 15) * 4]) = q4;
        for (int i = t; i < NV * 16; i += 256) {
            int v = i >> 4, c = (i & 15) * 4;
            *(float4*)(embsh + v * ESTR + c) = *(const float4*)(ek_g + v * DD + c);
        }
        for (int i = t; i < QBLK * NV; i += 256) w_lds[i] = 0.f;
    }
    __syncthreads();

    // ---- Phase B: qe[r][v] = (q[r].emb_k[v])/8 ----
    for (int i = t; i < QBLK * NV; i += 256) {
        int r = i / NV, v = i - r * NV;
        float acc = 0.f;
        #pragma unroll 8
        for (int d = 0; d < DD; ++d)
            acc += bf2f(Qb[r][d]) * embsh[v * ESTR + d];
        qe_lds[i] = acc * SCALE;
    }
    __syncthreads();

    // ---- Phase C: e = exp(QK^T/8 + qe) -> bf16 P in LDS (swizzled) ----
    {
        const int ar = lane & 15, akg = lane >> 4;
        bf16x8 aF0 = *(const bf16x8*)&Qb[ar][akg * 8];
        bf16x8 aF1 = *(const bf16x8*)&Qb[ar][32 + akg * 8];
        const short* kbase = kb + (size_t)bh * TT * DD;
        #pragma unroll 2
        for (int nt = 0; nt < 16; ++nt) {
            int s0 = wave * 256 + nt * 16;
            const short* kp = kbase + (s0 + ar) * DD + akg * 8;
            bf16x8 bF0 = *(const bf16x8*)kp;
            bf16x8 bF1 = *(const bf16x8*)(kp + 32);
            f32x4 acc = {0.f, 0.f, 0.f, 0.f};
            acc = __builtin_amdgcn_mfma_f32_16x16x32_bf16(aF0, bF0, acc, 0, 0, 0);
            acc = __builtin_amdgcn_mfma_f32_16x16x32_bf16(aF1, bF1, acc, 0, 0, 0);
            int sC = s0 + ar;
            int rb = akg * 4;
            #pragma unroll
            for (int j = 0; j < 4; ++j) {
                int r = rb + j;
                int dlt = sC - (q0 + r);
                dlt = dlt < -MAXREL ? -MAXREL : (dlt > MAXREL ? MAXREL : dlt);
                float lg = acc[j] * SCALE + qe_lds[r * NV + dlt + MAXREL];
                float e = __expf(lg);
                *(short*)(pbuf + r * 2048 + ((2 * sC) ^ ((r & 7) << 4))) = f2bf(e);
            }
        }
    }
    __syncthreads();

    // ---- Phase D: row sums (chunked), w scatter, attn write; stage emb_v ----
    for (int i = t; i < NV * 16; i += 256) {
        int v = i >> 4, c = (i & 15) * 4;
        *(float4*)(embsh + v * ESTR + c) = *(const float4*)(ev_g + v * DD + c);
    }
    {
        float* ab = attn_g + ((size_t)bh * TT + q0) * TT;
        #pragma unroll
        for (int j = 0; j < 4; ++j) {
            const int r  = wave * 4 + j;
            const int tq = q0 + r;
            const int X  = (r & 7) << 4;
            float e[16];
            #pragma unroll
            for (int i = 0; i < 4; ++i) {
                bf16x4 p4 = *(const bf16x4*)(pbuf + r * 2048 + ((8 * lane + 512 * i) ^ X));
                e[4*i+0] = bf2f(p4[0]); e[4*i+1] = bf2f(p4[1]);
                e[4*i+2] = bf2f(p4[2]); e[4*i+3] = bf2f(p4[3]);
            }
            float sum = 0.f, suff = 0.f, msum = 0.f;
            #pragma unroll
            for (int i = 0; i < 4; ++i) {
                int sb = lane * 4 + 256 * i;
                float csum = (e[4*i] + e[4*i+1]) + (e[4*i+2] + e[4*i+3]);
                sum += csum;
                if (sb >= tq + MAXREL) {
                    suff += csum;
                } else if (sb + 3 >= tq + MAXREL) {
                    #pragma unroll
                    for (int ii = 0; ii < 4; ++ii)
                        if (sb + ii >= tq + MAXREL) suff += e[4*i+ii];
                }
                if (sb + 3 > tq - MAXREL && sb < tq + MAXREL) {
                    #pragma unroll
                    for (int ii = 0; ii < 4; ++ii) {
                        int d = sb + ii - tq;
                        if (d > -MAXREL && d < MAXREL) {
                            w_lds[r * NV + d + MAXREL] = e[4*i+ii];
                            msum += e[4*i+ii];
                        }
                    }
                }
            }
            #pragma unroll
            for (int off = 32; off; off >>= 1) {
                sum  += __shfl_xor(sum, off);
                suff += __shfl_xor(suff, off);
                msum += __shfl_xor(msum, off);
            }
            float inv = 1.0f / sum;
            if (lane == 0) {
                inv_lds[r] = inv;
                w_lds[r * NV]      = sum - suff - msum;   // pref
                w_lds[r * NV + 32] = suff;
            }
            #pragma unroll
            for (int i = 0; i < 4; ++i) {
                float4 o;
                o.x = e[4*i+0] * inv; o.y = e[4*i+1] * inv;
                o.z = e[4*i+2] * inv; o.w = e[4*i+3] * inv;
                *(float4*)(ab + (size_t)r * TT + lane * 4 + 256 * i) = o;
            }
        }
    }
    __syncthreads();

    // ---- Phase F: out = inv * (P V + w . emb_v) ----
    {
        const int lc = lane & 15, a = lane >> 4;
        const int dcol = wave * 16 + lc;
        const short* vbase = vt + ((size_t)bh * DD + dcol) * TT;
        f32x4 acc = {0.f, 0.f, 0.f, 0.f};
        #pragma unroll 4
        for (int kt = 0; kt < 32; ++kt) {
            bf16x8 aF = *(const bf16x8*)(pbuf + lc * 2048 + ((kt * 64 + a * 16) ^ ((lc & 7) << 4)));
            bf16x8 bF = *(const bf16x8*)(vbase + kt * 32 + a * 8);
            acc = __builtin_amdgcn_mfma_f32_16x16x32_bf16(aF, bF, acc, 0, 0, 0);
        }
        const int rb = a * 4;
        #pragma unroll
        for (int j = 0; j < 4; ++j) {
            const int r = rb + j;
            float o = acc[j];
            #pragma unroll 8
            for (int v = 0; v < NV; ++v)
                o += w_lds[r * NV + v] * embsh[v * ESTR + dcol];
            out_g[((size_t)bh * TT + q0 + r) * DD + dcol] = o * inv_lds[r];
        }
    }
}

extern "C" void kernel_launch(void* const* d_in, const int* in_sizes, int n_in,
                              void* d_out, int out_size, void* d_ws, size_t ws_size,
                              hipStream_t stream) {
    const float* q  = (const float*)d_in[0];
    const float* k  = (const float*)d_in[1];
    const float* v  = (const float*)d_in[2];
    const float* ek = (const float*)d_in[3];
    const float* ev = (const float*)d_in[4];
    float* out  = (float*)d_out;
    float* attn = out + (size_t)BH * TT * DD;

    short* kbuf = (short*)d_ws;
    short* vtb  = kbuf + (size_t)BH * TT * DD;

    convk_kernel<<<dim3(2048), dim3(256), 0, stream>>>(k, kbuf);
    transv_kernel<<<dim3(1024), dim3(256), 0, stream>>>(v, vtb);
    relattn_kernel<<<dim3(4096), dim3(256), 0, stream>>>(q, kbuf, vtb, ek, ev, out, attn);
}

// Round 4
// 170.602 us; speedup vs baseline: 2.0160x; 1.3057x over previous
//
#include <hip/hip_runtime.h>

#define TT 1024
#define DD 64
#define MAXREL 16
#define NV 33
#define QBLK 16
#define SCALE 0.125f
#define BH 64

typedef short bf16x8 __attribute__((ext_vector_type(8)));
typedef short bf16x4 __attribute__((ext_vector_type(4)));
typedef float f32x4 __attribute__((ext_vector_type(4)));

static __device__ inline short f2bf(float f) {
    union { float f; unsigned u; } x; x.f = f;
    unsigned u = x.u;
    u += 0x7fff + ((u >> 16) & 1);   // RNE
    return (short)(u >> 16);
}
static __device__ inline float bf2f(short s) {
    union { unsigned u; float f; } x;
    x.u = ((unsigned)(unsigned short)s) << 16;
    return x.f;
}
static __device__ inline bf16x8 pack8(float4 a, float4 b) {
    bf16x8 r;
    r[0]=f2bf(a.x); r[1]=f2bf(a.y); r[2]=f2bf(a.z); r[3]=f2bf(a.w);
    r[4]=f2bf(b.x); r[5]=f2bf(b.y); r[6]=f2bf(b.z); r[7]=f2bf(b.w);
    return r;
}

// ---- pre-kernel 1: K f32 -> bf16 ----
__global__ __launch_bounds__(256)
void convk_kernel(const float* __restrict__ src, short* __restrict__ dst) {
    size_t i = (size_t)blockIdx.x * 256 + threadIdx.x;
    const float4* s = (const float4*)(src + i * 8);
    float4 a = s[0], b = s[1];
    bf16x8 r;
    r[0]=f2bf(a.x); r[1]=f2bf(a.y); r[2]=f2bf(a.z); r[3]=f2bf(a.w);
    r[4]=f2bf(b.x); r[5]=f2bf(b.y); r[6]=f2bf(b.z); r[7]=f2bf(b.w);
    *(bf16x8*)(dst + i * 8) = r;
}

// ---- pre-kernel 2: V [bh][s][d] f32 -> vt [bh][d][s] bf16 ----
__global__ __launch_bounds__(256)
void transv_kernel(const float* __restrict__ v, short* __restrict__ vt) {
    int bh = blockIdx.x >> 4;
    int st = blockIdx.x & 15;
    int wave = threadIdx.x >> 6, lane = threadIdx.x & 63;
    int s0 = st * 64 + wave * 16;
    const float* vp = v + ((size_t)bh * TT + s0) * DD + lane;
    bf16x8 lo, hi;
    #pragma unroll
    for (int e = 0; e < 8; ++e) lo[e] = f2bf(vp[(size_t)e * DD]);
    #pragma unroll
    for (int e = 0; e < 8; ++e) hi[e] = f2bf(vp[(size_t)(e + 8) * DD]);
    short* dp = vt + ((size_t)bh * DD + lane) * TT + s0;
    *(bf16x8*)dp = lo;
    *(bf16x8*)(dp + 8) = hi;
}

__global__ __launch_bounds__(256, 4)
void relattn_kernel(const float* __restrict__ q_g,
                    const short* __restrict__ kb,
                    const short* __restrict__ vt,
                    const float* __restrict__ ek_g,
                    const float* __restrict__ ev_g,
                    float* __restrict__ out_g,
                    float* __restrict__ attn_g) {
    __shared__ __align__(16) char pbuf[QBLK * 2048];     // 32768 B bf16 P, swizzled
    __shared__ float qe_lds[QBLK * NV];                  // 2112 B
    __shared__ float w_lds[QBLK * NV];                   // 2112 B (unnormalized)
    __shared__ float psum_lds[QBLK][4];                  // 256 B
    __shared__ float psuf_lds[QBLK][4];
    __shared__ float pmid_lds[QBLK][4];
    __shared__ float inv_lds[QBLK];

    const int t    = threadIdx.x;
    const int bid  = blockIdx.x;
    const int wg   = ((bid & 7) << 9) | (bid >> 3);      // XCD swizzle
    const int bh   = wg >> 6;
    const int q0   = (wg & 63) * QBLK;
    const int wave = t >> 6;
    const int lane = t & 63;
    const int lr   = lane & 15;                          // q-row index in fragments
    const int akg  = lane >> 4;

    // Q fragment (B operand of swapped MFMA): Q[q0+lr][akg*8 + ...]
    bf16x8 qF0, qF1;
    {
        const float* qp = q_g + ((size_t)bh * TT + q0 + lr) * DD + akg * 8;
        float4 a = *(const float4*)qp,       b = *(const float4*)(qp + 4);
        float4 c = *(const float4*)(qp + 32), d = *(const float4*)(qp + 36);
        qF0 = pack8(a, b); qF1 = pack8(c, d);
    }

    // ---- Phase A: zero w; qe via MFMA (waves 0..2: v-tile = wave*16..+16) ----
    for (int i = t; i < QBLK * NV; i += 256) w_lds[i] = 0.f;
    if (wave < 3) {
        int v = wave * 16 + lr; if (v > 32) v = 32;      // clamp duplicate rows
        const float* ep = ek_g + v * DD + akg * 8;
        float4 a = *(const float4*)ep,       b = *(const float4*)(ep + 4);
        float4 c = *(const float4*)(ep + 32), d = *(const float4*)(ep + 36);
        bf16x8 eF0 = pack8(a, b), eF1 = pack8(c, d);
        f32x4 qacc = {0.f, 0.f, 0.f, 0.f};
        qacc = __builtin_amdgcn_mfma_f32_16x16x32_bf16(eF0, qF0, qacc, 0, 0, 0);
        qacc = __builtin_amdgcn_mfma_f32_16x16x32_bf16(eF1, qF1, qacc, 0, 0, 0);
        // lane holds (r = lr, v = wave*16 + akg*4 + j)
        #pragma unroll
        for (int j = 0; j < 4; ++j) {
            int vv = wave * 16 + akg * 4 + j;
            if (vv < NV) qe_lds[lr * NV + vv] = qacc[j] * SCALE;
        }
    }
    __syncthreads();

    // ---- Phase C: swapped QK^T -> exp -> bf16 P (b64 stores) + per-lane sums ----
    {
        const short* kbase = kb + (size_t)bh * TT * DD;
        const int tq = q0 + lr;
        const int X  = (lr & 7) << 4;
        float sum = 0.f, suff = 0.f, msum = 0.f;
        #pragma unroll 2
        for (int nt = 0; nt < 16; ++nt) {
            int s0 = wave * 256 + nt * 16;
            const short* kp = kbase + (size_t)(s0 + lr) * DD + akg * 8;
            bf16x8 kF0 = *(const bf16x8*)kp;
            bf16x8 kF1 = *(const bf16x8*)(kp + 32);
            f32x4 acc = {0.f, 0.f, 0.f, 0.f};
            acc = __builtin_amdgcn_mfma_f32_16x16x32_bf16(kF0, qF0, acc, 0, 0, 0);
            acc = __builtin_amdgcn_mfma_f32_16x16x32_bf16(kF1, qF1, acc, 0, 0, 0);
            // lane holds S^T: (q-row = lr, s = s0 + akg*4 + j)
            const int sb = s0 + akg * 4;
            float e[4];
            #pragma unroll
            for (int j = 0; j < 4; ++j) {
                int dlt = sb + j - tq;
                dlt = dlt < -MAXREL ? -MAXREL : (dlt > MAXREL ? MAXREL : dlt);
                e[j] = __expf(acc[j] * SCALE + qe_lds[lr * NV + dlt + MAXREL]);
            }
            float csum = (e[0] + e[1]) + (e[2] + e[3]);
            sum += csum;
            if (sb >= tq + MAXREL) {
                suff += csum;
            } else if (sb + 3 >= tq + MAXREL) {
                #pragma unroll
                for (int j = 0; j < 4; ++j)
                    if (sb + j >= tq + MAXREL) suff += e[j];
            }
            if (sb + 3 > tq - MAXREL && sb < tq + MAXREL) {
                #pragma unroll
                for (int j = 0; j < 4; ++j) {
                    int d = sb + j - tq;
                    if (d > -MAXREL && d < MAXREL) {
                        w_lds[lr * NV + d + MAXREL] = e[j];
                        msum += e[j];
                    }
                }
            }
            bf16x4 p4;
            p4[0]=f2bf(e[0]); p4[1]=f2bf(e[1]); p4[2]=f2bf(e[2]); p4[3]=f2bf(e[3]);
            *(bf16x4*)(pbuf + lr * 2048 + ((2 * sb) ^ X)) = p4;
        }
        sum  += __shfl_xor(sum, 16);  sum  += __shfl_xor(sum, 32);
        suff += __shfl_xor(suff, 16); suff += __shfl_xor(suff, 32);
        msum += __shfl_xor(msum, 16); msum += __shfl_xor(msum, 32);
        if (lane < 16) {
            psum_lds[lr][wave] = sum;
            psuf_lds[lr][wave] = suff;
            pmid_lds[lr][wave] = msum;
        }
    }
    __syncthreads();

    // ---- D1: finalize per-row sums (16 threads) ----
    if (t < QBLK) {
        float s  = (psum_lds[t][0] + psum_lds[t][1]) + (psum_lds[t][2] + psum_lds[t][3]);
        float sf = (psuf_lds[t][0] + psuf_lds[t][1]) + (psuf_lds[t][2] + psuf_lds[t][3]);
        float sm = (pmid_lds[t][0] + pmid_lds[t][1]) + (pmid_lds[t][2] + pmid_lds[t][3]);
        inv_lds[t] = 1.0f / s;
        w_lds[t * NV]      = s - sf - sm;   // prefix weight (v=0)
        w_lds[t * NV + 32] = sf;            // suffix weight (v=32)
    }
    __syncthreads();

    // ---- Phase F: out = inv * (P V + w . emb_v) ----
    {
        const int dcol = wave * 16 + lr;
        const short* vbase = vt + ((size_t)bh * DD + dcol) * TT;
        const int X = (lr & 7) << 4;
        f32x4 acc = {0.f, 0.f, 0.f, 0.f};
        #pragma unroll 8
        for (int kt = 0; kt < 32; ++kt) {
            bf16x8 aF = *(const bf16x8*)(pbuf + lr * 2048 + ((kt * 64 + akg * 16) ^ X));
            bf16x8 bF = *(const bf16x8*)(vbase + kt * 32 + akg * 8);
            acc = __builtin_amdgcn_mfma_f32_16x16x32_bf16(aF, bF, acc, 0, 0, 0);
        }
        float o0 = acc[0], o1 = acc[1], o2 = acc[2], o3 = acc[3];
        const int rb = akg * 4;
        #pragma unroll 8
        for (int v = 0; v < NV; ++v) {
            float ev = ev_g[v * DD + dcol];
            o0 += w_lds[(rb + 0) * NV + v] * ev;
            o1 += w_lds[(rb + 1) * NV + v] * ev;
            o2 += w_lds[(rb + 2) * NV + v] * ev;
            o3 += w_lds[(rb + 3) * NV + v] * ev;
        }
        float* op = out_g + ((size_t)bh * TT + q0 + rb) * DD + dcol;
        op[0 * DD] = o0 * inv_lds[rb + 0];
        op[1 * DD] = o1 * inv_lds[rb + 1];
        op[2 * DD] = o2 * inv_lds[rb + 2];
        op[3 * DD] = o3 * inv_lds[rb + 3];
    }

    // ---- D2: normalized attn write (nontemporal, coalesced) ----
    {
        float* ab = attn_g + ((size_t)bh * TT + q0) * TT;
        #pragma unroll
        for (int j = 0; j < 4; ++j) {
            const int r = wave * 4 + j;
            const float inv = inv_lds[r];
            const int X = (r & 7) << 4;
            #pragma unroll
            for (int i = 0; i < 4; ++i) {
                bf16x4 p4 = *(const bf16x4*)(pbuf + r * 2048 + ((8 * lane + 512 * i) ^ X));
                f32x4 o;
                o[0] = bf2f(p4[0]) * inv; o[1] = bf2f(p4[1]) * inv;
                o[2] = bf2f(p4[2]) * inv; o[3] = bf2f(p4[3]) * inv;
                __builtin_nontemporal_store(o, (f32x4*)(ab + (size_t)r * TT + lane * 4 + 256 * i));
            }
        }
    }
}

extern "C" void kernel_launch(void* const* d_in, const int* in_sizes, int n_in,
                              void* d_out, int out_size, void* d_ws, size_t ws_size,
                              hipStream_t stream) {
    const float* q  = (const float*)d_in[0];
    const float* k  = (const float*)d_in[1];
    const float* v  = (const float*)d_in[2];
    const float* ek = (const float*)d_in[3];
    const float* ev = (const float*)d_in[4];
    float* out  = (float*)d_out;
    float* attn = out + (size_t)BH * TT * DD;

    short* kbuf = (short*)d_ws;
    short* vtb  = kbuf + (size_t)BH * TT * DD;

    convk_kernel<<<dim3(2048), dim3(256), 0, stream>>>(k, kbuf);
    transv_kernel<<<dim3(1024), dim3(256), 0, stream>>>(v, vtb);
    relattn_kernel<<<dim3(4096), dim3(256), 0, stream>>>(q, kbuf, vtb, ek, ev, out, attn);
}